// Round 20
// baseline (139.462 us; speedup 1.0000x reference)
//
#include <hip/hip_runtime.h>
#include <hip/hip_bf16.h>

#define N_NODES 50000
#define N_EDGES 400000
#define DIM     128
#define NREL    8
#define NBASES  4
#define KCAT    1152            // 8*128 relation slices + 128 self-loop
#define NKS     36              // KCAT/32
#define TN      16              // nodes per mega-block (proven shape)
#define TROW    2304            // Tcat bf16 row stride bytes; XOR swizzle fixes banks

typedef __hip_bfloat16 bf16;

typedef __bf16 bf16x8 __attribute__((ext_vector_type(8)));
typedef float  f32x4  __attribute__((ext_vector_type(4)));

union frag_u { bf16x8 v; bf16 e[8]; };
union pack4_u { unsigned long long ll; bf16 b[4]; };

// ---- workspace layout (bytes) ----
// hb16  bf16 [N][D]          : 12,800,000
// recs  uint2 [E]            :  3,200,000  ((dst,et)-sorted; key=(src<<3)|et)
// hist2 int [N*8]            :  1,600,000
// cur2  int [N*8]            :  1,600,000
// deg   int [N] pad          :    200,064
// base  int [N+1] pad        :    200,064
// WcatF bf16 [8][36][64][8]  :    294,912  (fragment-ordered stacked weights)
// fwF   bf16 [8][4][64][8]   :     32,768  (fragment-ordered ffn_w)
#define HB16_OFF  0LL
#define RECS_OFF  12800000LL
#define HIST_OFF  16000000LL
#define CUR2_OFF  17600000LL
#define DEG_OFF   19200000LL
#define BASE_OFF  19400064LL
#define WCAT_OFF  19600128LL
#define FWF_OFF   19895040LL
#define WS_NEEDED 19927808LL

__device__ __forceinline__ int swzb(int row) { return (row & 15) << 4; }  // 256B rows
__device__ __forceinline__ int swzy(int row) { return (row & 31) << 4; }  // 512B rows
__device__ __forceinline__ int swzt(int row) { return (row & 7) << 4; }   // Tcat rows (stride 2304)

// ---------------------------------------------------------------------------
// K_prep: hb16 = bf16(h); hist2[(dst,et)]++; WcatF/fwF in FRAGMENT ORDER:
//   WcatF element (ct,ks,l,j) = Wcat^T[ct*16+(l&15)][ks*32+(l>>4)*8+j]
__global__ __launch_bounds__(256)
void k_prep(const float* __restrict__ h, const float* __restrict__ V,
            const float* __restrict__ wc,
            const float* __restrict__ loop_w, const float* __restrict__ ffn_w,
            const int* __restrict__ dst, const int* __restrict__ et,
            bf16* __restrict__ hb, bf16* __restrict__ WcatF,
            bf16* __restrict__ fwF, int* __restrict__ hist2) {
    int p = blockIdx.x * 256 + threadIdx.x;
    if (p < N_NODES * DIM / 8) {
        const float* s = h + (long long)p * 8;
        f32x4 lo = *(const f32x4*)s, hi = *(const f32x4*)(s + 4);
        frag_u o;
#pragma unroll
        for (int j = 0; j < 4; ++j) {
            o.e[j]     = __float2bfloat16(lo[j]);
            o.e[4 + j] = __float2bfloat16(hi[j]);
        }
        *(bf16x8*)(hb + (long long)p * 8) = o.v;
    }
    if (p < N_EDGES) atomicAdd(&hist2[dst[p] * 8 + et[p]], 1);
    if (p < 8 * NKS * 64 * 8) {            // 147456 WcatF elements
        int idx = p;
        int j = idx & 7; idx >>= 3;
        int l = idx & 63; idx >>= 6;
        int ks = idx % NKS, ct = idx / NKS;
        int col = ct * 16 + (l & 15);
        int k = ks * 32 + (l >> 4) * 8 + j;
        float val;
        if (k < 1024) {
            int r = k >> 7, i = k & 127;
            val = 0.f;
#pragma unroll
            for (int b = 0; b < NBASES; ++b)
                val += wc[r * NBASES + b] * V[(b << 14) + i * DIM + col];
        } else {
            val = loop_w[(k - 1024) * DIM + col];
        }
        WcatF[p] = __float2bfloat16(val);
    }
    if (p < 8 * 4 * 64 * 8) {              // 16384 fwF elements
        int idx = p;
        int j = idx & 7; idx >>= 3;
        int l = idx & 63; idx >>= 6;
        int ks = idx & 3, ct = idx >> 2;
        int col = ct * 16 + (l & 15);
        int k = ks * 32 + (l >> 4) * 8 + j;
        fwF[p] = __float2bfloat16(ffn_w[col * DIM + k]);   // ffn_w[o][i]
    }
}

// ---------------------------------------------------------------------------
// K_deg: deg[d] = sum_et hist2[d][et]
__global__ __launch_bounds__(256)
void k_deg(const int* __restrict__ hist2, int* __restrict__ deg) {
    int d = blockIdx.x * 256 + threadIdx.x;
    if (d < N_NODES) {
        int4 a = *(const int4*)(hist2 + d * 8);
        int4 b = *(const int4*)(hist2 + d * 8 + 4);
        deg[d] = a.x + a.y + a.z + a.w + b.x + b.y + b.z + b.w;
    }
}

// ---------------------------------------------------------------------------
// K_scan: exclusive prefix sum of deg -> base. 1 block, 1024 thr.
#define SCAN_V 13
__global__ __launch_bounds__(1024)
void k_scan(const int* __restrict__ deg, int* __restrict__ base) {
    __shared__ int wsum[16];
    const int t = threadIdx.x, lane = t & 63, wv = t >> 6;
    const int i0 = t * (SCAN_V * 4);
    int4 v[SCAN_V];
#pragma unroll
    for (int i = 0; i < SCAN_V; ++i) {
        int idx = i0 + i * 4;
        if (idx + 3 < N_NODES) v[i] = *(const int4*)(deg + idx);
        else {
            v[i].x = (idx + 0 < N_NODES) ? deg[idx + 0] : 0;
            v[i].y = (idx + 1 < N_NODES) ? deg[idx + 1] : 0;
            v[i].z = (idx + 2 < N_NODES) ? deg[idx + 2] : 0;
            v[i].w = (idx + 3 < N_NODES) ? deg[idx + 3] : 0;
        }
    }
    int s = 0;
#pragma unroll
    for (int i = 0; i < SCAN_V; ++i) s += v[i].x + v[i].y + v[i].z + v[i].w;
    int inc = s;
#pragma unroll
    for (int m = 1; m < 64; m <<= 1) {
        int u = __shfl_up(inc, m);
        if (lane >= m) inc += u;
    }
    if (lane == 63) wsum[wv] = inc;
    __syncthreads();
    if (t < 16) {
        int w = wsum[t];
        int winc = w;
#pragma unroll
        for (int m = 1; m < 16; m <<= 1) {
            int u = __shfl_up(winc, m);
            if (t >= m) winc += u;
        }
        wsum[t] = winc - w;
    }
    __syncthreads();
    int run = wsum[wv] + (inc - s);
#pragma unroll
    for (int i = 0; i < SCAN_V; ++i) {
        int idx = i0 + i * 4;
        if (idx + 3 < N_NODES) {
            int4 o;
            o.x = run; o.y = o.x + v[i].x; o.z = o.y + v[i].y; o.w = o.z + v[i].z;
            run = o.w + v[i].w;
            *(int4*)(base + idx) = o;
        } else {
            if (idx + 0 < N_NODES) { base[idx+0] = run; run += v[i].x; }
            if (idx + 1 < N_NODES) { base[idx+1] = run; run += v[i].y; }
            if (idx + 2 < N_NODES) { base[idx+2] = run; run += v[i].z; }
            if (idx + 3 < N_NODES) { base[idx+3] = run; run += v[i].w; }
        }
    }
    if (t == 1023) base[N_NODES] = run;
}

// ---------------------------------------------------------------------------
// K_sub: cur2[d][et] = base[d] + exclusive-prefix_et(hist2[d][.])
__global__ __launch_bounds__(256)
void k_sub(const int* __restrict__ hist2, const int* __restrict__ base,
           int* __restrict__ cur2) {
    int d = blockIdx.x * 256 + threadIdx.x;
    if (d < N_NODES) {
        int4 a = *(const int4*)(hist2 + d * 8);
        int4 b = *(const int4*)(hist2 + d * 8 + 4);
        int run = base[d];
        int4 oa, ob;
        oa.x = run; run += a.x;
        oa.y = run; run += a.y;
        oa.z = run; run += a.z;
        oa.w = run; run += a.w;
        ob.x = run; run += b.x;
        ob.y = run; run += b.y;
        ob.z = run; run += b.z;
        ob.w = run;
        *(int4*)(cur2 + d * 8)     = oa;
        *(int4*)(cur2 + d * 8 + 4) = ob;
    }
}

// ---------------------------------------------------------------------------
// K_scatter: bucket edges by (dst, et). recs = {(src<<3)|et, bits(norm)}.
__global__ __launch_bounds__(256)
void k_scatter(const int* __restrict__ src, const int* __restrict__ dst,
               const int* __restrict__ et, const float* __restrict__ norm,
               int* __restrict__ cur2, uint2* __restrict__ recs) {
    int e = blockIdx.x * 256 + threadIdx.x;
    if (e >= N_EDGES) return;
    int d = dst[e], r = et[e];
    int pos = atomicAdd(&cur2[d * 8 + r], 1);
    uint2 rc;
    rc.x = ((unsigned)src[e] << 3) | (unsigned)r;
    rc.y = __float_as_uint(norm[e]);
    recs[pos] = rc;
}

// ---------------------------------------------------------------------------
// K_mega: 16 nodes/block, 256 thr (4 waves), LDS 40,960 B EXACT -> 4 blocks/CU.
//  P1b gather: 8-edge unroll; all 8 row loads are PINNED before the STEP chain
//  via __builtin_amdgcn_sched_barrier(0) so 8 x 256B are genuinely in flight
//  (R19 showed the scheduler otherwise sinks each load to its use, VGPR=52).
//  Rest verbatim R19: Tcat stride 2304 + XOR swzt; P2/P3 fragment-ordered B;
//  P4 LayerNorm.
__global__ __launch_bounds__(256, 4)
void k_mega(const bf16* __restrict__ hb16, const uint2* __restrict__ recs,
            const int* __restrict__ base, const bf16* __restrict__ WcatF,
            const float* __restrict__ bias,
            const bf16* __restrict__ fwF, const float* __restrict__ ffn_b,
            const float* __restrict__ ln_g, const float* __restrict__ ln_b,
            float* __restrict__ out) {
    __shared__ __align__(16) char Tf[TN * TROW];    // 36,864 B bf16 Tcat
    __shared__ __align__(16) char hnb[TN * 256];    // 4 KB bf16 swz
    char* aggy = Tf;                                // 8 KB alias for P3/P4
    const int t = threadIdx.x, wv = t >> 6, l = t & 63;
    const int n0 = blockIdx.x * TN;

    // ---- P0: zero relation region [0, 2048)B of each row (XOR-invariant) ----
    {
        const f32x4 z4{0.f, 0.f, 0.f, 0.f};
#pragma unroll
        for (int u = t; u < TN * 128; u += 256) {
            int row = u >> 7, off = (u & 127) * 16;
            *(f32x4*)(Tf + row * TROW + off) = z4;
        }
    }
    __syncthreads();

    const int grp = t >> 4, c = t & 15;
    const int n = n0 + grp;
    const long long nc = (n < N_NODES) ? n : (N_NODES - 1);
    const int rowb = grp * TROW;
    const int xt = swzt(grp);

    // ---- P1a: self-loop slice (in-row bytes 2048..2304, XOR'd) ----
    *(bf16x8*)(Tf + rowb + ((2048 + c * 16) ^ xt)) =
        *(const bf16x8*)(hb16 + nc * DIM + c * 8);

    // ---- P1b: gather (sorted runs -> reg acc + flush per et), 8-edge unroll,
    //           metadata broadcast loads; loads pinned before compute ----
    if (n < N_NODES) {
        const int b0 = base[n], b1 = base[n + 1];
        float acc[8];
#pragma unroll
        for (int q = 0; q < 8; ++q) acc[q] = 0.f;
        int cur_et = -1;

        auto flush = [&]() {
            frag_u o;
#pragma unroll
            for (int q = 0; q < 8; ++q) o.e[q] = __float2bfloat16(acc[q]);
            *(bf16x8*)(Tf + rowb + ((cur_et * 256 + c * 16) ^ xt)) = o.v;
#pragma unroll
            for (int q = 0; q < 8; ++q) acc[q] = 0.f;
        };

        for (int eb = b0; eb < b1; eb += 8) {
            const int rem = b1 - eb;
            const uint2 m0 = recs[eb + 0];
            const uint2 m1 = recs[eb + 1];
            const uint2 m2 = recs[eb + 2];
            const uint2 m3 = recs[eb + 3];
            const uint2 m4 = recs[eb + 4];
            const uint2 m5 = recs[eb + 5];
            const uint2 m6 = recs[eb + 6];
            const uint2 m7 = recs[eb + 7];
            __builtin_amdgcn_sched_barrier(0);   // recs loads issued first
            frag_u f0, f1, f2, f3, f4, f5, f6, f7;  // 8 indep loads in flight
            f0.v = *(const bf16x8*)(hb16 + (long long)(m0.x >> 3) * DIM + c * 8);
            f1.v = *(const bf16x8*)(hb16 + (long long)(m1.x >> 3) * DIM + c * 8);
            f2.v = *(const bf16x8*)(hb16 + (long long)(m2.x >> 3) * DIM + c * 8);
            f3.v = *(const bf16x8*)(hb16 + (long long)(m3.x >> 3) * DIM + c * 8);
            f4.v = *(const bf16x8*)(hb16 + (long long)(m4.x >> 3) * DIM + c * 8);
            f5.v = *(const bf16x8*)(hb16 + (long long)(m5.x >> 3) * DIM + c * 8);
            f6.v = *(const bf16x8*)(hb16 + (long long)(m6.x >> 3) * DIM + c * 8);
            f7.v = *(const bf16x8*)(hb16 + (long long)(m7.x >> 3) * DIM + c * 8);
            __builtin_amdgcn_sched_barrier(0);   // pin: all 8 issued before STEPs

#define STEP(K, MK, FK)                                                  \
            if (K < rem) {                                               \
                const int et_ = (int)(MK.x & 7u);                        \
                const float w_ = __uint_as_float(MK.y);                  \
                if (et_ != cur_et) {                                     \
                    if (cur_et >= 0) flush();                            \
                    cur_et = et_;                                        \
                }                                                        \
                _Pragma("unroll")                                        \
                for (int q = 0; q < 8; ++q)                              \
                    acc[q] = fmaf(w_, __bfloat162float(FK.e[q]), acc[q]);\
            }
            STEP(0, m0, f0)
            STEP(1, m1, f1)
            STEP(2, m2, f2)
            STEP(3, m3, f3)
            STEP(4, m4, f4)
            STEP(5, m5, f5)
            STEP(6, m6, f6)
            STEP(7, m7, f7)
#undef STEP
        }
        if (cur_et >= 0) flush();
    }
    __syncthreads();

    // ---- P2: hn = relu(Tcat @ Wcat + bias), K=1152.
    //      Wave wv: col tiles ct0=wv, ct1=wv+4; rows 0..15 (row = lrow).
    //      One A-read per ks feeds both MFMAs. A addr XOR'd with swzt(lrow). ----
    const int lrow = l & 15, kgrp = l >> 4;
    const int ct0 = wv, ct1 = wv + 4;
    const int xa = swzt(lrow);
    {
        f32x4 acc1[2];
#pragma unroll
        for (int ci = 0; ci < 2; ++ci) acc1[ci] = f32x4{0.f, 0.f, 0.f, 0.f};
        const bf16* Bf0 = WcatF + (long long)ct0 * NKS * 512;
        const bf16* Bf1 = WcatF + (long long)ct1 * NKS * 512;
#pragma unroll 4
        for (int ks = 0; ks < NKS; ++ks) {
            frag_u b0, b1, a;
            b0.v = *(const bf16x8*)(Bf0 + ks * 512 + l * 8);  // coalesced 1KB
            b1.v = *(const bf16x8*)(Bf1 + ks * 512 + l * 8);  // coalesced 1KB
            a.v  = *(const bf16x8*)(Tf + lrow * TROW +
                                    ((ks * 64 + kgrp * 16) ^ xa));
            acc1[0] = __builtin_amdgcn_mfma_f32_16x16x32_bf16(
                b0.v, a.v, acc1[0], 0, 0, 0);
            acc1[1] = __builtin_amdgcn_mfma_f32_16x16x32_bf16(
                b1.v, a.v, acc1[1], 0, 0, 0);
        }
#pragma unroll
        for (int ci = 0; ci < 2; ++ci) {
            const int col = (wv + ci * 4) * 16 + kgrp * 4;
            f32x4 bi = *(const f32x4*)(bias + col);
            pack4_u p;
#pragma unroll
            for (int j = 0; j < 4; ++j)
                p.b[j] = __float2bfloat16(fmaxf(acc1[ci][j] + bi[j], 0.f));
            *(unsigned long long*)(hnb + ((lrow * 256 + col * 2) ^ swzb(lrow))) = p.ll;
        }
    }
    __syncthreads();

    // ---- P3: y = hn @ ffn_w^T + ffn_b + h, K=128 -> aggy (aliases Tf) ----
    {
        f32x4 acc2[2];
#pragma unroll
        for (int ci = 0; ci < 2; ++ci) acc2[ci] = f32x4{0.f, 0.f, 0.f, 0.f};
        const bf16* Bf0 = fwF + (long long)ct0 * 4 * 512;
        const bf16* Bf1 = fwF + (long long)ct1 * 4 * 512;
#pragma unroll
        for (int ks = 0; ks < 4; ++ks) {
            frag_u b0, b1, a;
            b0.v = *(const bf16x8*)(Bf0 + ks * 512 + l * 8);  // coalesced 1KB
            b1.v = *(const bf16x8*)(Bf1 + ks * 512 + l * 8);  // coalesced 1KB
            a.v  = *(const bf16x8*)(hnb +
                     ((lrow * 256 + ks * 64 + kgrp * 16) ^ swzb(lrow)));
            acc2[0] = __builtin_amdgcn_mfma_f32_16x16x32_bf16(
                b0.v, a.v, acc2[0], 0, 0, 0);
            acc2[1] = __builtin_amdgcn_mfma_f32_16x16x32_bf16(
                b1.v, a.v, acc2[1], 0, 0, 0);
        }
        const long long gr = (n0 + lrow < N_NODES) ? (n0 + lrow) : (N_NODES - 1);
#pragma unroll
        for (int ci = 0; ci < 2; ++ci) {
            const int col = (wv + ci * 4) * 16 + kgrp * 4;
            f32x4 fb = *(const f32x4*)(ffn_b + col);
            pack4_u hp;
            hp.ll = *(const unsigned long long*)(hb16 + gr * DIM + col);
            f32x4 y;
#pragma unroll
            for (int j = 0; j < 4; ++j)
                y[j] = acc2[ci][j] + fb[j] + __bfloat162float(hp.b[j]);
            *(f32x4*)(aggy + lrow * 512 + ((col * 4) ^ swzy(lrow))) = y;
        }
    }
    __syncthreads();

    // ---- P4: LayerNorm. 4 waves x 4 rows. Addr swizzled; col = PRE-swz 2l. ----
#pragma unroll 1
    for (int jr = 0; jr < 4; ++jr) {
        const int row = wv * 4 + jr;
        const int nn = n0 + row;
        const int x = swzy(row);
        float2 yv = *(const float2*)(aggy + row * 512 + ((l * 8) ^ x));
        const int col = l * 2;
        float s = yv.x + yv.y, s2 = yv.x * yv.x + yv.y * yv.y;
#pragma unroll
        for (int m = 1; m < 64; m <<= 1) {
            s  += __shfl_xor(s, m);
            s2 += __shfl_xor(s2, m);
        }
        if (nn < N_NODES) {
            float mu  = s * (1.f / DIM);
            float var = s2 * (1.f / DIM) - mu * mu;
            float inv = rsqrtf(var + 1e-8f);
            float2 gv = *(const float2*)(ln_g + col);
            float2 bv = *(const float2*)(ln_b + col);
            float2 o2{(yv.x - mu) * inv * gv.x + bv.x,
                      (yv.y - mu) * inv * gv.y + bv.y};
            *(float2*)(out + (long long)nn * DIM + col) = o2;
        }
    }
}

// ---------------------------------------------------------------------------
extern "C" void kernel_launch(void* const* d_in, const int* in_sizes, int n_in,
                              void* d_out, int out_size, void* d_ws, size_t ws_size,
                              hipStream_t stream) {
    const float* h      = (const float*)d_in[0];
    const float* V      = (const float*)d_in[1];
    const float* w_comp = (const float*)d_in[2];
    const float* loop_w = (const float*)d_in[3];
    const float* bias   = (const float*)d_in[4];
    const float* ffn_w  = (const float*)d_in[5];
    const float* ffn_b  = (const float*)d_in[6];
    const float* ln_g   = (const float*)d_in[7];
    const float* ln_b   = (const float*)d_in[8];
    const float* norm   = (const float*)d_in[9];
    const int*   src    = (const int*)d_in[10];
    const int*   dst    = (const int*)d_in[11];
    const int*   etype  = (const int*)d_in[12];
    float* out = (float*)d_out;

    if (ws_size < (size_t)WS_NEEDED) return;

    char* ws = (char*)d_ws;
    bf16*  hb16  = (bf16*)(ws + HB16_OFF);
    uint2* recs  = (uint2*)(ws + RECS_OFF);
    int*   hist2 = (int*)(ws + HIST_OFF);
    int*   cur2  = (int*)(ws + CUR2_OFF);
    int*   deg   = (int*)(ws + DEG_OFF);
    int*   base  = (int*)(ws + BASE_OFF);
    bf16*  WcatF = (bf16*)(ws + WCAT_OFF);
    bf16*  fwF   = (bf16*)(ws + FWF_OFF);

    hipMemsetAsync(hist2, 0, N_NODES * NREL * sizeof(int), stream);

    k_prep<<<dim3(3125), dim3(256), 0, stream>>>(
        h, V, w_comp, loop_w, ffn_w, dst, etype, hb16, WcatF, fwF, hist2);

    k_deg<<<dim3((N_NODES + 255) / 256), dim3(256), 0, stream>>>(hist2, deg);
    k_scan<<<dim3(1), dim3(1024), 0, stream>>>(deg, base);
    k_sub<<<dim3((N_NODES + 255) / 256), dim3(256), 0, stream>>>(hist2, base, cur2);
    k_scatter<<<dim3((N_EDGES + 255) / 256), dim3(256), 0, stream>>>(
        src, dst, etype, norm, cur2, recs);

    k_mega<<<dim3((N_NODES + TN - 1) / TN), dim3(256), 0, stream>>>(
        hb16, recs, base, WcatF, bias, fwF, ffn_b, ln_g, ln_b, out);
}

// Round 21
// 123.073 us; speedup vs baseline: 1.1332x; 1.1332x over previous
//
#include <hip/hip_runtime.h>
#include <hip/hip_bf16.h>

#define N_NODES 50000
#define N_EDGES 400000
#define DIM     128
#define NREL    8
#define NBASES  4
#define KCAT    640             // 4*128 basis slices + 128 self-loop
#define NKS     20              // KCAT/32
#define TN      16              // nodes per mega-block (proven shape)
#define TROW    1280            // Tcat bf16 row stride bytes; XOR swzt fixes banks

typedef __hip_bfloat16 bf16;

typedef __bf16 bf16x8 __attribute__((ext_vector_type(8)));
typedef float  f32x4  __attribute__((ext_vector_type(4)));

union frag_u { bf16x8 v; bf16 e[8]; };
union pack4_u { unsigned long long ll; bf16 b[4]; };

// ---- workspace layout (bytes) ----
// hb16  bf16 [N][D]          : 12,800,000
// recs  uint2 [E]            :  3,200,000  ((dst,et)-sorted; key=(src<<3)|et)
// hist2 int [N*8]            :  1,600,000
// cur2  int [N*8]            :  1,600,000
// deg   int [N] pad          :    200,064
// base  int [N+1] pad        :    200,064
// WcatF bf16 [8][20][64][8]  :    163,840  (fragment-ordered [V_b; loop_w])
// fwF   bf16 [8][4][64][8]   :     32,768  (fragment-ordered ffn_w)
#define HB16_OFF  0LL
#define RECS_OFF  12800000LL
#define HIST_OFF  16000000LL
#define CUR2_OFF  17600000LL
#define DEG_OFF   19200000LL
#define BASE_OFF  19400064LL
#define WCAT_OFF  19600128LL
#define FWF_OFF   19763968LL
#define WS_NEEDED 19796736LL

__device__ __forceinline__ int swzb(int row) { return (row & 15) << 4; }  // 256B rows
__device__ __forceinline__ int swzy(int row) { return (row & 31) << 4; }  // 512B rows
__device__ __forceinline__ int swzt(int row) { return (row & 7) << 4; }   // Tcat rows

// ---------------------------------------------------------------------------
// K_prep: hb16 = bf16(h); hist2[(dst,et)]++; WcatF/fwF in FRAGMENT ORDER.
//   WcatF element (ct,ks,l,j): col=ct*16+(l&15), k=ks*32+(l>>4)*8+j;
//   k<512 -> V[k>>7][k&127][col]; k>=512 -> loop_w[k-512][col].
__global__ __launch_bounds__(256)
void k_prep(const float* __restrict__ h, const float* __restrict__ V,
            const float* __restrict__ loop_w, const float* __restrict__ ffn_w,
            const int* __restrict__ dst, const int* __restrict__ et,
            bf16* __restrict__ hb, bf16* __restrict__ WcatF,
            bf16* __restrict__ fwF, int* __restrict__ hist2) {
    int p = blockIdx.x * 256 + threadIdx.x;
    if (p < N_NODES * DIM / 8) {
        const float* s = h + (long long)p * 8;
        f32x4 lo = *(const f32x4*)s, hi = *(const f32x4*)(s + 4);
        frag_u o;
#pragma unroll
        for (int j = 0; j < 4; ++j) {
            o.e[j]     = __float2bfloat16(lo[j]);
            o.e[4 + j] = __float2bfloat16(hi[j]);
        }
        *(bf16x8*)(hb + (long long)p * 8) = o.v;
    }
    if (p < N_EDGES) atomicAdd(&hist2[dst[p] * 8 + et[p]], 1);
    if (p < 8 * NKS * 64 * 8) {            // 81,920 WcatF elements
        int idx = p;
        int j = idx & 7; idx >>= 3;
        int l = idx & 63; idx >>= 6;
        int ks = idx % NKS, ct = idx / NKS;
        int col = ct * 16 + (l & 15);
        int k = ks * 32 + (l >> 4) * 8 + j;
        float val;
        if (k < 512) {
            val = V[((k >> 7) << 14) + (k & 127) * DIM + col];
        } else {
            val = loop_w[(k - 512) * DIM + col];
        }
        WcatF[p] = __float2bfloat16(val);
    }
    if (p < 8 * 4 * 64 * 8) {              // 16384 fwF elements
        int idx = p;
        int j = idx & 7; idx >>= 3;
        int l = idx & 63; idx >>= 6;
        int ks = idx & 3, ct = idx >> 2;
        int col = ct * 16 + (l & 15);
        int k = ks * 32 + (l >> 4) * 8 + j;
        fwF[p] = __float2bfloat16(ffn_w[col * DIM + k]);   // ffn_w[o][i]
    }
}

// ---------------------------------------------------------------------------
// K_deg: deg[d] = sum_et hist2[d][et]
__global__ __launch_bounds__(256)
void k_deg(const int* __restrict__ hist2, int* __restrict__ deg) {
    int d = blockIdx.x * 256 + threadIdx.x;
    if (d < N_NODES) {
        int4 a = *(const int4*)(hist2 + d * 8);
        int4 b = *(const int4*)(hist2 + d * 8 + 4);
        deg[d] = a.x + a.y + a.z + a.w + b.x + b.y + b.z + b.w;
    }
}

// ---------------------------------------------------------------------------
// K_scan: exclusive prefix sum of deg -> base. 1 block, 1024 thr.
#define SCAN_V 13
__global__ __launch_bounds__(1024)
void k_scan(const int* __restrict__ deg, int* __restrict__ base) {
    __shared__ int wsum[16];
    const int t = threadIdx.x, lane = t & 63, wv = t >> 6;
    const int i0 = t * (SCAN_V * 4);
    int4 v[SCAN_V];
#pragma unroll
    for (int i = 0; i < SCAN_V; ++i) {
        int idx = i0 + i * 4;
        if (idx + 3 < N_NODES) v[i] = *(const int4*)(deg + idx);
        else {
            v[i].x = (idx + 0 < N_NODES) ? deg[idx + 0] : 0;
            v[i].y = (idx + 1 < N_NODES) ? deg[idx + 1] : 0;
            v[i].z = (idx + 2 < N_NODES) ? deg[idx + 2] : 0;
            v[i].w = (idx + 3 < N_NODES) ? deg[idx + 3] : 0;
        }
    }
    int s = 0;
#pragma unroll
    for (int i = 0; i < SCAN_V; ++i) s += v[i].x + v[i].y + v[i].z + v[i].w;
    int inc = s;
#pragma unroll
    for (int m = 1; m < 64; m <<= 1) {
        int u = __shfl_up(inc, m);
        if (lane >= m) inc += u;
    }
    if (lane == 63) wsum[wv] = inc;
    __syncthreads();
    if (t < 16) {
        int w = wsum[t];
        int winc = w;
#pragma unroll
        for (int m = 1; m < 16; m <<= 1) {
            int u = __shfl_up(winc, m);
            if (t >= m) winc += u;
        }
        wsum[t] = winc - w;
    }
    __syncthreads();
    int run = wsum[wv] + (inc - s);
#pragma unroll
    for (int i = 0; i < SCAN_V; ++i) {
        int idx = i0 + i * 4;
        if (idx + 3 < N_NODES) {
            int4 o;
            o.x = run; o.y = o.x + v[i].x; o.z = o.y + v[i].y; o.w = o.z + v[i].z;
            run = o.w + v[i].w;
            *(int4*)(base + idx) = o;
        } else {
            if (idx + 0 < N_NODES) { base[idx+0] = run; run += v[i].x; }
            if (idx + 1 < N_NODES) { base[idx+1] = run; run += v[i].y; }
            if (idx + 2 < N_NODES) { base[idx+2] = run; run += v[i].z; }
            if (idx + 3 < N_NODES) { base[idx+3] = run; run += v[i].w; }
        }
    }
    if (t == 1023) base[N_NODES] = run;
}

// ---------------------------------------------------------------------------
// K_sub: cur2[d][et] = base[d] + exclusive-prefix_et(hist2[d][.])
__global__ __launch_bounds__(256)
void k_sub(const int* __restrict__ hist2, const int* __restrict__ base,
           int* __restrict__ cur2) {
    int d = blockIdx.x * 256 + threadIdx.x;
    if (d < N_NODES) {
        int4 a = *(const int4*)(hist2 + d * 8);
        int4 b = *(const int4*)(hist2 + d * 8 + 4);
        int run = base[d];
        int4 oa, ob;
        oa.x = run; run += a.x;
        oa.y = run; run += a.y;
        oa.z = run; run += a.z;
        oa.w = run; run += a.w;
        ob.x = run; run += b.x;
        ob.y = run; run += b.y;
        ob.z = run; run += b.z;
        ob.w = run;
        *(int4*)(cur2 + d * 8)     = oa;
        *(int4*)(cur2 + d * 8 + 4) = ob;
    }
}

// ---------------------------------------------------------------------------
// K_scatter: bucket edges by (dst, et). recs = {(src<<3)|et, bits(norm)}.
__global__ __launch_bounds__(256)
void k_scatter(const int* __restrict__ src, const int* __restrict__ dst,
               const int* __restrict__ et, const float* __restrict__ norm,
               int* __restrict__ cur2, uint2* __restrict__ recs) {
    int e = blockIdx.x * 256 + threadIdx.x;
    if (e >= N_EDGES) return;
    int d = dst[e], r = et[e];
    int pos = atomicAdd(&cur2[d * 8 + r], 1);
    uint2 rc;
    rc.x = ((unsigned)src[e] << 3) | (unsigned)r;
    rc.y = __float_as_uint(norm[e]);
    recs[pos] = rc;
}

// ---------------------------------------------------------------------------
// K_mega (basis-space): 16 nodes/block, 256 thr (4 waves),
//  LDS 24,704 B -> 6 blocks/CU.
//  Gather accumulates U_b = sum_e (wc[et,b]*norm)*h[src] in acc[4][8] f32 regs
//  (coefs via one f32x4 LDS read per edge from the 128B wcs table). No P0
//  zeroing, no per-et flush: one unconditional 4-slice store per node.
//  P2: hn = relu([U_0..U_3; h] @ [V_0..V_3; loop_w] + bias), K=640 (NKS=20);
//  B-traffic/block 164KB (0.56x of R20). P3 fwF. P4 LayerNorm.
__global__ __launch_bounds__(256, 6)
void k_mega(const bf16* __restrict__ hb16, const uint2* __restrict__ recs,
            const int* __restrict__ base, const float* __restrict__ wc,
            const bf16* __restrict__ WcatF, const float* __restrict__ bias,
            const bf16* __restrict__ fwF, const float* __restrict__ ffn_b,
            const float* __restrict__ ln_g, const float* __restrict__ ln_b,
            float* __restrict__ out) {
    __shared__ __align__(16) char Tf[TN * TROW];    // 20,480 B bf16 Tcat
    __shared__ __align__(16) char hnb[TN * 256];    // 4 KB bf16 swz
    __shared__ __align__(16) float wcs[32];         // wc[8][4]
    char* aggy = Tf;                                // 8 KB alias for P3/P4
    const int t = threadIdx.x, wv = t >> 6, l = t & 63;
    const int n0 = blockIdx.x * TN;

    if (t < 32) wcs[t] = wc[t];
    __syncthreads();

    const int grp = t >> 4, c = t & 15;
    const int n = n0 + grp;                 // N_NODES = 3125*16: always valid
    const int rowb = grp * TROW;
    const int xt = swzt(grp);

    // ---- P1a: self-loop slice (in-row bytes 1024..1280, XOR'd) ----
    *(bf16x8*)(Tf + rowb + ((1024 + c * 16) ^ xt)) =
        *(const bf16x8*)(hb16 + (long long)n * DIM + c * 8);

    // ---- P1b: gather into 4 basis accumulators (regs), 4-edge unroll ----
    {
        const int b0 = base[n], b1 = base[n + 1];
        float acc[4][8];
#pragma unroll
        for (int b = 0; b < 4; ++b)
#pragma unroll
            for (int q = 0; q < 8; ++q) acc[b][q] = 0.f;

        for (int eb = b0; eb < b1; eb += 4) {
            const int rem = b1 - eb;
            const uint2 m0 = recs[eb + 0];
            const uint2 m1 = recs[eb + 1];
            const uint2 m2 = recs[eb + 2];
            const uint2 m3 = recs[eb + 3];
            frag_u f0, f1, f2, f3;   // 4 indep L2/L3 loads in flight
            f0.v = *(const bf16x8*)(hb16 + (long long)(m0.x >> 3) * DIM + c * 8);
            f1.v = *(const bf16x8*)(hb16 + (long long)(m1.x >> 3) * DIM + c * 8);
            f2.v = *(const bf16x8*)(hb16 + (long long)(m2.x >> 3) * DIM + c * 8);
            f3.v = *(const bf16x8*)(hb16 + (long long)(m3.x >> 3) * DIM + c * 8);

#define STEP(K, MK, FK)                                                   \
            if (K < rem) {                                                \
                const float w_ = __uint_as_float(MK.y);                   \
                f32x4 cb = *(const f32x4*)(wcs + (MK.x & 7u) * 4);        \
                _Pragma("unroll")                                         \
                for (int b = 0; b < 4; ++b) {                             \
                    const float cw = cb[b] * w_;                          \
                    _Pragma("unroll")                                     \
                    for (int q = 0; q < 8; ++q)                           \
                        acc[b][q] = fmaf(cw, __bfloat162float(FK.e[q]),   \
                                         acc[b][q]);                      \
                }                                                         \
            }
            STEP(0, m0, f0)
            STEP(1, m1, f1)
            STEP(2, m2, f2)
            STEP(3, m3, f3)
#undef STEP
        }

        // one unconditional store per basis slice
#pragma unroll
        for (int b = 0; b < 4; ++b) {
            frag_u o;
#pragma unroll
            for (int q = 0; q < 8; ++q) o.e[q] = __float2bfloat16(acc[b][q]);
            *(bf16x8*)(Tf + rowb + ((b * 256 + c * 16) ^ xt)) = o.v;
        }
    }
    __syncthreads();

    // ---- P2: hn = relu(Tcat @ Wcat + bias), K=640.
    //      Wave wv: col tiles ct0=wv, ct1=wv+4; rows 0..15 (row = lrow).
    //      One A-read per ks feeds both MFMAs. A addr XOR'd with swzt(lrow). ----
    const int lrow = l & 15, kgrp = l >> 4;
    const int ct0 = wv, ct1 = wv + 4;
    const int xa = swzt(lrow);
    {
        f32x4 acc1[2];
#pragma unroll
        for (int ci = 0; ci < 2; ++ci) acc1[ci] = f32x4{0.f, 0.f, 0.f, 0.f};
        const bf16* Bf0 = WcatF + (long long)ct0 * NKS * 512;
        const bf16* Bf1 = WcatF + (long long)ct1 * NKS * 512;
#pragma unroll 4
        for (int ks = 0; ks < NKS; ++ks) {
            frag_u b0, b1, a;
            b0.v = *(const bf16x8*)(Bf0 + ks * 512 + l * 8);  // coalesced 1KB
            b1.v = *(const bf16x8*)(Bf1 + ks * 512 + l * 8);  // coalesced 1KB
            a.v  = *(const bf16x8*)(Tf + lrow * TROW +
                                    ((ks * 64 + kgrp * 16) ^ xa));
            acc1[0] = __builtin_amdgcn_mfma_f32_16x16x32_bf16(
                b0.v, a.v, acc1[0], 0, 0, 0);
            acc1[1] = __builtin_amdgcn_mfma_f32_16x16x32_bf16(
                b1.v, a.v, acc1[1], 0, 0, 0);
        }
#pragma unroll
        for (int ci = 0; ci < 2; ++ci) {
            const int col = (wv + ci * 4) * 16 + kgrp * 4;
            f32x4 bi = *(const f32x4*)(bias + col);
            pack4_u p;
#pragma unroll
            for (int j = 0; j < 4; ++j)
                p.b[j] = __float2bfloat16(fmaxf(acc1[ci][j] + bi[j], 0.f));
            *(unsigned long long*)(hnb + ((lrow * 256 + col * 2) ^ swzb(lrow))) = p.ll;
        }
    }
    __syncthreads();

    // ---- P3: y = hn @ ffn_w^T + ffn_b + h, K=128 -> aggy (aliases Tf) ----
    {
        f32x4 acc2[2];
#pragma unroll
        for (int ci = 0; ci < 2; ++ci) acc2[ci] = f32x4{0.f, 0.f, 0.f, 0.f};
        const bf16* Bf0 = fwF + (long long)ct0 * 4 * 512;
        const bf16* Bf1 = fwF + (long long)ct1 * 4 * 512;
#pragma unroll
        for (int ks = 0; ks < 4; ++ks) {
            frag_u b0, b1, a;
            b0.v = *(const bf16x8*)(Bf0 + ks * 512 + l * 8);  // coalesced 1KB
            b1.v = *(const bf16x8*)(Bf1 + ks * 512 + l * 8);  // coalesced 1KB
            a.v  = *(const bf16x8*)(hnb +
                     ((lrow * 256 + ks * 64 + kgrp * 16) ^ swzb(lrow)));
            acc2[0] = __builtin_amdgcn_mfma_f32_16x16x32_bf16(
                b0.v, a.v, acc2[0], 0, 0, 0);
            acc2[1] = __builtin_amdgcn_mfma_f32_16x16x32_bf16(
                b1.v, a.v, acc2[1], 0, 0, 0);
        }
        const long long gr = n0 + lrow;
#pragma unroll
        for (int ci = 0; ci < 2; ++ci) {
            const int col = (wv + ci * 4) * 16 + kgrp * 4;
            f32x4 fb = *(const f32x4*)(ffn_b + col);
            pack4_u hp;
            hp.ll = *(const unsigned long long*)(hb16 + gr * DIM + col);
            f32x4 y;
#pragma unroll
            for (int j = 0; j < 4; ++j)
                y[j] = acc2[ci][j] + fb[j] + __bfloat162float(hp.b[j]);
            *(f32x4*)(aggy + lrow * 512 + ((col * 4) ^ swzy(lrow))) = y;
        }
    }
    __syncthreads();

    // ---- P4: LayerNorm. 4 waves x 4 rows. Addr swizzled; col = PRE-swz 2l. ----
#pragma unroll 1
    for (int jr = 0; jr < 4; ++jr) {
        const int row = wv * 4 + jr;
        const int nn = n0 + row;
        const int x = swzy(row);
        float2 yv = *(const float2*)(aggy + row * 512 + ((l * 8) ^ x));
        const int col = l * 2;
        float s = yv.x + yv.y, s2 = yv.x * yv.x + yv.y * yv.y;
#pragma unroll
        for (int m = 1; m < 64; m <<= 1) {
            s  += __shfl_xor(s, m);
            s2 += __shfl_xor(s2, m);
        }
        float mu  = s * (1.f / DIM);
        float var = s2 * (1.f / DIM) - mu * mu;
        float inv = rsqrtf(var + 1e-8f);
        float2 gv = *(const float2*)(ln_g + col);
        float2 bv = *(const float2*)(ln_b + col);
        float2 o2{(yv.x - mu) * inv * gv.x + bv.x,
                  (yv.y - mu) * inv * gv.y + bv.y};
        *(float2*)(out + (long long)nn * DIM + col) = o2;
    }
}

// ---------------------------------------------------------------------------
extern "C" void kernel_launch(void* const* d_in, const int* in_sizes, int n_in,
                              void* d_out, int out_size, void* d_ws, size_t ws_size,
                              hipStream_t stream) {
    const float* h      = (const float*)d_in[0];
    const float* V      = (const float*)d_in[1];
    const float* w_comp = (const float*)d_in[2];
    const float* loop_w = (const float*)d_in[3];
    const float* bias   = (const float*)d_in[4];
    const float* ffn_w  = (const float*)d_in[5];
    const float* ffn_b  = (const float*)d_in[6];
    const float* ln_g   = (const float*)d_in[7];
    const float* ln_b   = (const float*)d_in[8];
    const float* norm   = (const float*)d_in[9];
    const int*   src    = (const int*)d_in[10];
    const int*   dst    = (const int*)d_in[11];
    const int*   etype  = (const int*)d_in[12];
    float* out = (float*)d_out;

    if (ws_size < (size_t)WS_NEEDED) return;

    char* ws = (char*)d_ws;
    bf16*  hb16  = (bf16*)(ws + HB16_OFF);
    uint2* recs  = (uint2*)(ws + RECS_OFF);
    int*   hist2 = (int*)(ws + HIST_OFF);
    int*   cur2  = (int*)(ws + CUR2_OFF);
    int*   deg   = (int*)(ws + DEG_OFF);
    int*   base  = (int*)(ws + BASE_OFF);
    bf16*  WcatF = (bf16*)(ws + WCAT_OFF);
    bf16*  fwF   = (bf16*)(ws + FWF_OFF);

    hipMemsetAsync(hist2, 0, N_NODES * NREL * sizeof(int), stream);

    k_prep<<<dim3(3125), dim3(256), 0, stream>>>(
        h, V, loop_w, ffn_w, dst, etype, hb16, WcatF, fwF, hist2);

    k_deg<<<dim3((N_NODES + 255) / 256), dim3(256), 0, stream>>>(hist2, deg);
    k_scan<<<dim3(1), dim3(1024), 0, stream>>>(deg, base);
    k_sub<<<dim3((N_NODES + 255) / 256), dim3(256), 0, stream>>>(hist2, base, cur2);
    k_scatter<<<dim3((N_EDGES + 255) / 256), dim3(256), 0, stream>>>(
        src, dst, etype, norm, cur2, recs);

    k_mega<<<dim3(N_NODES / TN), dim3(256), 0, stream>>>(
        hb16, recs, base, w_comp, WcatF, bias, fwF, ffn_b, ln_g, ln_b, out);
}

// Round 22
// 115.769 us; speedup vs baseline: 1.2047x; 1.0631x over previous
//
#include <hip/hip_runtime.h>
#include <hip/hip_bf16.h>

#define N_NODES 50000
#define N_EDGES 400000
#define DIM     128
#define NREL    8
#define NBASES  4
#define KCAT    640             // 4*128 basis slices + 128 self-loop
#define NKS     20              // KCAT/32
#define TN      16              // nodes per mega-block (proven shape)
#define TROW    1280            // Tcat bf16 row stride bytes; XOR swzt fixes banks

typedef __hip_bfloat16 bf16;

typedef __bf16 bf16x8 __attribute__((ext_vector_type(8)));
typedef float  f32x4  __attribute__((ext_vector_type(4)));

union frag_u { bf16x8 v; bf16 e[8]; };
union pack4_u { unsigned long long ll; bf16 b[4]; };

// ---- workspace layout (bytes) ----
// hb16  bf16 [N][D]          : 12,800,000
// recs  uint2 [E]            :  3,200,000  (dst-bucketed; key=(src<<3)|et)
// hist  int [N] + counter    :    200,064  (memset 0; counter at hist[N])
// seg   uint2 [N]            :    400,064  ({beg,end} per node)
// cur   int [N]              :    200,064  (scatter cursors)
// WcatF bf16 [8][20][64][8]  :    163,840  (fragment-ordered [V_b; loop_w])
// fwF   bf16 [8][4][64][8]   :     32,768  (fragment-ordered ffn_w)
#define HB16_OFF  0LL
#define RECS_OFF  12800000LL
#define HIST_OFF  16000000LL
#define SEG_OFF   16200064LL
#define CUR_OFF   16600128LL
#define WCAT_OFF  16800192LL
#define FWF_OFF   16964032LL
#define WS_NEEDED 16996800LL

__device__ __forceinline__ int swzb(int row) { return (row & 15) << 4; }  // 256B rows
__device__ __forceinline__ int swzy(int row) { return (row & 31) << 4; }  // 512B rows
__device__ __forceinline__ int swzt(int row) { return (row & 7) << 4; }   // Tcat rows

// ---------------------------------------------------------------------------
// K_prep: hb16 = bf16(h); hist[dst]++; WcatF/fwF in FRAGMENT ORDER.
//   WcatF element (ct,ks,l,j): col=ct*16+(l&15), k=ks*32+(l>>4)*8+j;
//   k<512 -> V[k>>7][k&127][col]; k>=512 -> loop_w[k-512][col].
__global__ __launch_bounds__(256)
void k_prep(const float* __restrict__ h, const float* __restrict__ V,
            const float* __restrict__ loop_w, const float* __restrict__ ffn_w,
            const int* __restrict__ dst,
            bf16* __restrict__ hb, bf16* __restrict__ WcatF,
            bf16* __restrict__ fwF, int* __restrict__ hist) {
    int p = blockIdx.x * 256 + threadIdx.x;
    if (p < N_NODES * DIM / 8) {
        const float* s = h + (long long)p * 8;
        f32x4 lo = *(const f32x4*)s, hi = *(const f32x4*)(s + 4);
        frag_u o;
#pragma unroll
        for (int j = 0; j < 4; ++j) {
            o.e[j]     = __float2bfloat16(lo[j]);
            o.e[4 + j] = __float2bfloat16(hi[j]);
        }
        *(bf16x8*)(hb + (long long)p * 8) = o.v;
    }
    if (p < N_EDGES) atomicAdd(&hist[dst[p]], 1);
    if (p < 8 * NKS * 64 * 8) {            // 81,920 WcatF elements
        int idx = p;
        int j = idx & 7; idx >>= 3;
        int l = idx & 63; idx >>= 6;
        int ks = idx % NKS, ct = idx / NKS;
        int col = ct * 16 + (l & 15);
        int k = ks * 32 + (l >> 4) * 8 + j;
        float val;
        if (k < 512) {
            val = V[((k >> 7) << 14) + (k & 127) * DIM + col];
        } else {
            val = loop_w[(k - 512) * DIM + col];
        }
        WcatF[p] = __float2bfloat16(val);
    }
    if (p < 8 * 4 * 64 * 8) {              // 16384 fwF elements
        int idx = p;
        int j = idx & 7; idx >>= 3;
        int l = idx & 63; idx >>= 6;
        int ks = idx & 3, ct = idx >> 2;
        int col = ct * 16 + (l & 15);
        int k = ks * 32 + (l >> 4) * 8 + j;
        fwF[p] = __float2bfloat16(ffn_w[col * DIM + k]);   // ffn_w[o][i]
    }
}

// ---------------------------------------------------------------------------
// K_alloc: segment allocation via wave prefix + one atomic per wave.
// seg[d] = {pos, pos+deg}; cur[d] = pos. Segment ORDER is nondeterministic,
// which is numerically irrelevant (per-node edge sets unchanged).
__global__ __launch_bounds__(256)
void k_alloc(const int* __restrict__ hist, int* __restrict__ counter,
             uint2* __restrict__ seg, int* __restrict__ cur) {
    const int d = blockIdx.x * 256 + threadIdx.x;
    const int lane = threadIdx.x & 63;
    int deg = (d < N_NODES) ? hist[d] : 0;
    int inc = deg;
#pragma unroll
    for (int m = 1; m < 64; m <<= 1) {
        int u = __shfl_up(inc, m);
        if (lane >= m) inc += u;
    }
    int basew = 0;
    if (lane == 63) basew = atomicAdd(counter, inc);   // inc@63 = wave total
    basew = __shfl(basew, 63);
    const int pos = basew + inc - deg;                 // exclusive prefix
    if (d < N_NODES) {
        seg[d] = uint2{(unsigned)pos, (unsigned)(pos + deg)};
        cur[d] = pos;
    }
}

// ---------------------------------------------------------------------------
// K_scatter: bucket edges by dst. recs = {(src<<3)|et, bits(norm)}.
__global__ __launch_bounds__(256)
void k_scatter(const int* __restrict__ src, const int* __restrict__ dst,
               const int* __restrict__ et, const float* __restrict__ norm,
               int* __restrict__ cur, uint2* __restrict__ recs) {
    int e = blockIdx.x * 256 + threadIdx.x;
    if (e >= N_EDGES) return;
    int d = dst[e];
    int pos = atomicAdd(&cur[d], 1);
    uint2 rc;
    rc.x = ((unsigned)src[e] << 3) | (unsigned)et[e];
    rc.y = __float_as_uint(norm[e]);
    recs[pos] = rc;
}

// ---------------------------------------------------------------------------
// K_mega (basis-space, verbatim R21 except seg[] lookup):
//  16 nodes/block, 256 thr (4 waves), LDS 24,704 B -> 6 blocks/CU.
//  Gather accumulates U_b = sum_e (wc[et,b]*norm)*h[src] in acc[4][8] f32 regs.
//  P2: hn = relu([U_0..U_3; h] @ [V_0..V_3; loop_w] + bias), K=640 (NKS=20).
//  P3 fwF. P4 LayerNorm.
__global__ __launch_bounds__(256, 6)
void k_mega(const bf16* __restrict__ hb16, const uint2* __restrict__ recs,
            const uint2* __restrict__ seg, const float* __restrict__ wc,
            const bf16* __restrict__ WcatF, const float* __restrict__ bias,
            const bf16* __restrict__ fwF, const float* __restrict__ ffn_b,
            const float* __restrict__ ln_g, const float* __restrict__ ln_b,
            float* __restrict__ out) {
    __shared__ __align__(16) char Tf[TN * TROW];    // 20,480 B bf16 Tcat
    __shared__ __align__(16) char hnb[TN * 256];    // 4 KB bf16 swz
    __shared__ __align__(16) float wcs[32];         // wc[8][4]
    char* aggy = Tf;                                // 8 KB alias for P3/P4
    const int t = threadIdx.x, wv = t >> 6, l = t & 63;
    const int n0 = blockIdx.x * TN;

    if (t < 32) wcs[t] = wc[t];
    __syncthreads();

    const int grp = t >> 4, c = t & 15;
    const int n = n0 + grp;                 // N_NODES = 3125*16: always valid
    const int rowb = grp * TROW;
    const int xt = swzt(grp);

    // ---- P1a: self-loop slice (in-row bytes 1024..1280, XOR'd) ----
    *(bf16x8*)(Tf + rowb + ((1024 + c * 16) ^ xt)) =
        *(const bf16x8*)(hb16 + (long long)n * DIM + c * 8);

    // ---- P1b: gather into 4 basis accumulators (regs), 4-edge unroll ----
    {
        const uint2 sg = seg[n];
        const int b0 = (int)sg.x, b1 = (int)sg.y;
        float acc[4][8];
#pragma unroll
        for (int b = 0; b < 4; ++b)
#pragma unroll
            for (int q = 0; q < 8; ++q) acc[b][q] = 0.f;

        for (int eb = b0; eb < b1; eb += 4) {
            const int rem = b1 - eb;
            const uint2 m0 = recs[eb + 0];
            const uint2 m1 = recs[eb + 1];
            const uint2 m2 = recs[eb + 2];
            const uint2 m3 = recs[eb + 3];
            frag_u f0, f1, f2, f3;   // 4 indep L2/L3 loads in flight
            f0.v = *(const bf16x8*)(hb16 + (long long)(m0.x >> 3) * DIM + c * 8);
            f1.v = *(const bf16x8*)(hb16 + (long long)(m1.x >> 3) * DIM + c * 8);
            f2.v = *(const bf16x8*)(hb16 + (long long)(m2.x >> 3) * DIM + c * 8);
            f3.v = *(const bf16x8*)(hb16 + (long long)(m3.x >> 3) * DIM + c * 8);

#define STEP(K, MK, FK)                                                   \
            if (K < rem) {                                                \
                const float w_ = __uint_as_float(MK.y);                   \
                f32x4 cb = *(const f32x4*)(wcs + (MK.x & 7u) * 4);        \
                _Pragma("unroll")                                         \
                for (int b = 0; b < 4; ++b) {                             \
                    const float cw = cb[b] * w_;                          \
                    _Pragma("unroll")                                     \
                    for (int q = 0; q < 8; ++q)                           \
                        acc[b][q] = fmaf(cw, __bfloat162float(FK.e[q]),   \
                                         acc[b][q]);                      \
                }                                                         \
            }
            STEP(0, m0, f0)
            STEP(1, m1, f1)
            STEP(2, m2, f2)
            STEP(3, m3, f3)
#undef STEP
        }

        // one unconditional store per basis slice
#pragma unroll
        for (int b = 0; b < 4; ++b) {
            frag_u o;
#pragma unroll
            for (int q = 0; q < 8; ++q) o.e[q] = __float2bfloat16(acc[b][q]);
            *(bf16x8*)(Tf + rowb + ((b * 256 + c * 16) ^ xt)) = o.v;
        }
    }
    __syncthreads();

    // ---- P2: hn = relu(Tcat @ Wcat + bias), K=640.
    //      Wave wv: col tiles ct0=wv, ct1=wv+4; rows 0..15 (row = lrow).
    //      One A-read per ks feeds both MFMAs. A addr XOR'd with swzt(lrow). ----
    const int lrow = l & 15, kgrp = l >> 4;
    const int ct0 = wv, ct1 = wv + 4;
    const int xa = swzt(lrow);
    {
        f32x4 acc1[2];
#pragma unroll
        for (int ci = 0; ci < 2; ++ci) acc1[ci] = f32x4{0.f, 0.f, 0.f, 0.f};
        const bf16* Bf0 = WcatF + (long long)ct0 * NKS * 512;
        const bf16* Bf1 = WcatF + (long long)ct1 * NKS * 512;
#pragma unroll 4
        for (int ks = 0; ks < NKS; ++ks) {
            frag_u b0, b1, a;
            b0.v = *(const bf16x8*)(Bf0 + ks * 512 + l * 8);  // coalesced 1KB
            b1.v = *(const bf16x8*)(Bf1 + ks * 512 + l * 8);  // coalesced 1KB
            a.v  = *(const bf16x8*)(Tf + lrow * TROW +
                                    ((ks * 64 + kgrp * 16) ^ xa));
            acc1[0] = __builtin_amdgcn_mfma_f32_16x16x32_bf16(
                b0.v, a.v, acc1[0], 0, 0, 0);
            acc1[1] = __builtin_amdgcn_mfma_f32_16x16x32_bf16(
                b1.v, a.v, acc1[1], 0, 0, 0);
        }
#pragma unroll
        for (int ci = 0; ci < 2; ++ci) {
            const int col = (wv + ci * 4) * 16 + kgrp * 4;
            f32x4 bi = *(const f32x4*)(bias + col);
            pack4_u p;
#pragma unroll
            for (int j = 0; j < 4; ++j)
                p.b[j] = __float2bfloat16(fmaxf(acc1[ci][j] + bi[j], 0.f));
            *(unsigned long long*)(hnb + ((lrow * 256 + col * 2) ^ swzb(lrow))) = p.ll;
        }
    }
    __syncthreads();

    // ---- P3: y = hn @ ffn_w^T + ffn_b + h, K=128 -> aggy (aliases Tf) ----
    {
        f32x4 acc2[2];
#pragma unroll
        for (int ci = 0; ci < 2; ++ci) acc2[ci] = f32x4{0.f, 0.f, 0.f, 0.f};
        const bf16* Bf0 = fwF + (long long)ct0 * 4 * 512;
        const bf16* Bf1 = fwF + (long long)ct1 * 4 * 512;
#pragma unroll
        for (int ks = 0; ks < 4; ++ks) {
            frag_u b0, b1, a;
            b0.v = *(const bf16x8*)(Bf0 + ks * 512 + l * 8);  // coalesced 1KB
            b1.v = *(const bf16x8*)(Bf1 + ks * 512 + l * 8);  // coalesced 1KB
            a.v  = *(const bf16x8*)(hnb +
                     ((lrow * 256 + ks * 64 + kgrp * 16) ^ swzb(lrow)));
            acc2[0] = __builtin_amdgcn_mfma_f32_16x16x32_bf16(
                b0.v, a.v, acc2[0], 0, 0, 0);
            acc2[1] = __builtin_amdgcn_mfma_f32_16x16x32_bf16(
                b1.v, a.v, acc2[1], 0, 0, 0);
        }
        const long long gr = n0 + lrow;
#pragma unroll
        for (int ci = 0; ci < 2; ++ci) {
            const int col = (wv + ci * 4) * 16 + kgrp * 4;
            f32x4 fb = *(const f32x4*)(ffn_b + col);
            pack4_u hp;
            hp.ll = *(const unsigned long long*)(hb16 + gr * DIM + col);
            f32x4 y;
#pragma unroll
            for (int j = 0; j < 4; ++j)
                y[j] = acc2[ci][j] + fb[j] + __bfloat162float(hp.b[j]);
            *(f32x4*)(aggy + lrow * 512 + ((col * 4) ^ swzy(lrow))) = y;
        }
    }
    __syncthreads();

    // ---- P4: LayerNorm. 4 waves x 4 rows. Addr swizzled; col = PRE-swz 2l. ----
#pragma unroll 1
    for (int jr = 0; jr < 4; ++jr) {
        const int row = wv * 4 + jr;
        const int nn = n0 + row;
        const int x = swzy(row);
        float2 yv = *(const float2*)(aggy + row * 512 + ((l * 8) ^ x));
        const int col = l * 2;
        float s = yv.x + yv.y, s2 = yv.x * yv.x + yv.y * yv.y;
#pragma unroll
        for (int m = 1; m < 64; m <<= 1) {
            s  += __shfl_xor(s, m);
            s2 += __shfl_xor(s2, m);
        }
        float mu  = s * (1.f / DIM);
        float var = s2 * (1.f / DIM) - mu * mu;
        float inv = rsqrtf(var + 1e-8f);
        float2 gv = *(const float2*)(ln_g + col);
        float2 bv = *(const float2*)(ln_b + col);
        float2 o2{(yv.x - mu) * inv * gv.x + bv.x,
                  (yv.y - mu) * inv * gv.y + bv.y};
        *(float2*)(out + (long long)nn * DIM + col) = o2;
    }
}

// ---------------------------------------------------------------------------
extern "C" void kernel_launch(void* const* d_in, const int* in_sizes, int n_in,
                              void* d_out, int out_size, void* d_ws, size_t ws_size,
                              hipStream_t stream) {
    const float* h      = (const float*)d_in[0];
    const float* V      = (const float*)d_in[1];
    const float* w_comp = (const float*)d_in[2];
    const float* loop_w = (const float*)d_in[3];
    const float* bias   = (const float*)d_in[4];
    const float* ffn_w  = (const float*)d_in[5];
    const float* ffn_b  = (const float*)d_in[6];
    const float* ln_g   = (const float*)d_in[7];
    const float* ln_b   = (const float*)d_in[8];
    const float* norm   = (const float*)d_in[9];
    const int*   src    = (const int*)d_in[10];
    const int*   dst    = (const int*)d_in[11];
    const int*   etype  = (const int*)d_in[12];
    float* out = (float*)d_out;

    if (ws_size < (size_t)WS_NEEDED) return;

    char* ws = (char*)d_ws;
    bf16*  hb16  = (bf16*)(ws + HB16_OFF);
    uint2* recs  = (uint2*)(ws + RECS_OFF);
    int*   hist  = (int*)(ws + HIST_OFF);
    int*   counter = hist + N_NODES;        // inside HIST region
    uint2* seg   = (uint2*)(ws + SEG_OFF);
    int*   cur   = (int*)(ws + CUR_OFF);
    bf16*  WcatF = (bf16*)(ws + WCAT_OFF);
    bf16*  fwF   = (bf16*)(ws + FWF_OFF);

    hipMemsetAsync(hist, 0, (N_NODES + 16) * sizeof(int), stream);

    k_prep<<<dim3(3125), dim3(256), 0, stream>>>(
        h, V, loop_w, ffn_w, dst, hb16, WcatF, fwF, hist);

    k_alloc<<<dim3((N_NODES + 255) / 256), dim3(256), 0, stream>>>(
        hist, counter, seg, cur);

    k_scatter<<<dim3((N_EDGES + 255) / 256), dim3(256), 0, stream>>>(
        src, dst, etype, norm, cur, recs);

    k_mega<<<dim3(N_NODES / TN), dim3(256), 0, stream>>>(
        hb16, recs, seg, w_comp, WcatF, bias, fwF, ffn_b, ln_g, ln_b, out);
}